// Round 14
// baseline (347.094 us; speedup 1.0000x reference)
//
#include <hip/hip_runtime.h>
#include <hip/hip_bf16.h>
#include <math.h>
#include <float.h>

typedef __attribute__((ext_vector_type(8))) short s8bf;
typedef __attribute__((ext_vector_type(4))) float f32x4;

typedef const __attribute__((address_space(1))) void g_void;
typedef __attribute__((address_space(3))) void lds_void;

__device__ inline ushort f2bf(float x) {
    unsigned int u = __float_as_uint(x);
    unsigned int r = (u + 0x7FFFu + ((u >> 16) & 1u)) >> 16;
    return (ushort)r;
}
__device__ inline ushort f2bf_fast(float x) {
    return (ushort)((__float_as_uint(x) + 0x8000u) >> 16);
}
__device__ inline float2 bf2x2(unsigned int u) {
    float2 r;
    r.x = __uint_as_float(u << 16);
    r.y = __uint_as_float(u & 0xFFFF0000u);
    return r;
}

// ---------------------------------------------------------------------------
// fp32 -> bf16 bulk convert
// ---------------------------------------------------------------------------
__global__ __launch_bounds__(256) void k_cvt_bf16(
    const float* __restrict__ src, ushort* __restrict__ dst, size_t n)
{
    size_t i = ((size_t)blockIdx.x * 256 + threadIdx.x) * 4;
    size_t stride = (size_t)gridDim.x * 256 * 4;
    for (; i < n; i += stride) {
        float4 v = *(const float4*)(src + i);
        ushort4 o;
        o.x = f2bf(v.x); o.y = f2bf(v.y); o.z = f2bf(v.z); o.w = f2bf(v.w);
        *(ushort4*)(dst + i) = o;
    }
}

// per-thread source pointer: row = tid>>2, 16B slot (tid&3) XOR-swizzled by row
__device__ inline const ushort* stage_ptr(const ushort* M, size_t ld, int ra, int tid)
{
    const int row  = tid >> 2;
    const int slot = tid & 3;
    const int scol = ((slot ^ ((row >> 1) & 3)) << 3);
    return M + (size_t)(ra + row) * ld + scol;
}

// ===========================================================================
// 256-thread, 128x128-tile 2-phase machinery (projection GEMM + fallback)
// ===========================================================================
__device__ inline void stage_issue2(const ushort* pa, const ushort* pb,
                                    size_t off64a, size_t off64b,
                                    ushort* As, ushort* Bs, int tid)
{
    const int wb = (tid >> 6) << 9;
    __builtin_amdgcn_global_load_lds((g_void*)pa,            (lds_void*)(As + wb),        16, 0, 0);
    __builtin_amdgcn_global_load_lds((g_void*)(pa + off64a), (lds_void*)(As + 2048 + wb), 16, 0, 0);
    __builtin_amdgcn_global_load_lds((g_void*)pb,            (lds_void*)(Bs + wb),        16, 0, 0);
    __builtin_amdgcn_global_load_lds((g_void*)(pb + off64b), (lds_void*)(Bs + 2048 + wb), 16, 0, 0);
}

__device__ inline void mma_tile(const ushort* As, const ushort* Bs,
                                int wr, int wc, int lane, f32x4 acc[4][4])
{
    const int hi = lane >> 4, lo = lane & 15;
    const int soff = ((hi ^ ((lo >> 1) & 3)) << 3);
    s8bf af[4], bfr[4];
#pragma unroll
    for (int m = 0; m < 4; ++m)
        af[m] = *(const s8bf*)(As + (wr * 64 + m * 16 + lo) * 32 + soff);
#pragma unroll
    for (int n = 0; n < 4; ++n)
        bfr[n] = *(const s8bf*)(Bs + (wc * 64 + n * 16 + lo) * 32 + soff);
#pragma unroll
    for (int m = 0; m < 4; ++m)
#pragma unroll
        for (int n = 0; n < 4; ++n)
            acc[m][n] = __builtin_amdgcn_mfma_f32_16x16x32_bf16(
                af[m], bfr[n], acc[m][n], 0, 0, 0);
}

#define DBUF_DECL  __shared__ __align__(16) ushort Lds[2][8192]
#define AS(p) (&Lds[p][0])
#define BS(p) (&Lds[p][4096])

// ---------------------------------------------------------------------------
// Fused projections: z=0 -> za = a@Wa^T+ba ; z=1 -> zb = b@Wb^T+bb
// ---------------------------------------------------------------------------
__global__ __launch_bounds__(256) void k_mfma_gemm_bias2(
    const ushort* __restrict__ Aa, const ushort* __restrict__ Wa,
    const float* __restrict__ ba, float* __restrict__ Ca,
    const ushort* __restrict__ Ab, const ushort* __restrict__ Wb,
    const float* __restrict__ bb, float* __restrict__ Cb,
    int Ncols, int Kd)
{
    DBUF_DECL;
    const int z = blockIdx.z;
    const ushort* A = z ? Ab : Aa;
    const ushort* W = z ? Wb : Wa;
    const float* bias = z ? bb : ba;
    float* C = z ? Cb : Ca;

    const int tid = threadIdx.x, lane = tid & 63, wid = tid >> 6;
    const int wr = wid >> 1, wc = wid & 1;
    const int rbase = blockIdx.x * 128, cbase = blockIdx.y * 128;
    const int hi = lane >> 4, lo = lane & 15;
    const int KS = Kd >> 5;
    const size_t o64 = (size_t)64 * Kd;

    f32x4 acc[4][4];
#pragma unroll
    for (int m = 0; m < 4; ++m)
#pragma unroll
        for (int n = 0; n < 4; ++n)
#pragma unroll
            for (int j = 0; j < 4; ++j) acc[m][n][j] = 0.f;

    const ushort* pa = stage_ptr(A, Kd, rbase, tid);
    const ushort* pb = stage_ptr(W, Kd, cbase, tid);
    stage_issue2(pa, pb, o64, o64, AS(0), BS(0), tid);
    __syncthreads();
    int phase = 0;
    for (int ks = 0; ks < KS; ++ks) {
        pa += 32; pb += 32;
        if (ks + 1 < KS)
            stage_issue2(pa, pb, o64, o64, AS(phase ^ 1), BS(phase ^ 1), tid);
        mma_tile(AS(phase), BS(phase), wr, wc, lane, acc);
        __syncthreads();
        phase ^= 1;
    }
#pragma unroll
    for (int n = 0; n < 4; ++n) {
        int col = cbase + wc * 64 + n * 16 + lo;
        float bv = bias[col];
#pragma unroll
        for (int m = 0; m < 4; ++m)
#pragma unroll
            for (int j = 0; j < 4; ++j) {
                int row = rbase + wr * 64 + m * 16 + hi * 4 + j;
                C[(size_t)row * Ncols + col] = acc[m][n][j] + bv;
            }
    }
}

// ---------------------------------------------------------------------------
// Row L2-normalize both za and zb (blockIdx.y picks), fp32 in -> bf16 out.
// ---------------------------------------------------------------------------
__global__ __launch_bounds__(256) void k_normalize2(
    const float* __restrict__ Za, ushort* __restrict__ Zab,
    const float* __restrict__ Zb, ushort* __restrict__ Zbb, int N, int D)
{
    const float* Z = blockIdx.y ? Zb : Za;
    ushort* Zo = blockIdx.y ? Zbb : Zab;
    const int lane = threadIdx.x & 63, wid = threadIdx.x >> 6;
    const int row = blockIdx.x * 4 + wid;
    if (row >= N) return;
    const float4* p = (const float4*)(Z + (size_t)row * D);
    const int nf4 = D >> 2;
    float ss = 0.f;
    for (int f = lane; f < nf4; f += 64) {
        float4 v = p[f];
        ss += v.x * v.x + v.y * v.y + v.z * v.z + v.w * v.w;
    }
#pragma unroll
    for (int msk = 1; msk < 64; msk <<= 1) ss += __shfl_xor(ss, msk, 64);
    float sc = 1.0f / fmaxf(sqrtf(ss), 1e-12f);
    ushort4* pb = (ushort4*)(Zo + (size_t)row * D);
    for (int f = lane; f < nf4; f += 64) {
        float4 v = p[f];
        ushort4 u;
        u.x = f2bf(v.x * sc); u.y = f2bf(v.y * sc);
        u.z = f2bf(v.z * sc); u.w = f2bf(v.w * sc);
        pb[f] = u;
    }
}

// ---------------------------------------------------------------------------
// Row sum-of-squares (codebook norms). Wave per row.
// ---------------------------------------------------------------------------
__global__ __launch_bounds__(256) void k_rownorm2(
    const float* __restrict__ X, float* __restrict__ out, int N, int D)
{
    const int lane = threadIdx.x & 63, wid = threadIdx.x >> 6;
    const int row = blockIdx.x * 4 + wid;
    if (row >= N) return;
    const float4* p = (const float4*)(X + (size_t)row * D);
    const int nf4 = D >> 2;
    float ss = 0.f;
    for (int f = lane; f < nf4; f += 64) {
        float4 v = p[f];
        ss += v.x * v.x + v.y * v.y + v.z * v.z + v.w * v.w;
    }
#pragma unroll
    for (int msk = 1; msk < 64; msk <<= 1) ss += __shfl_xor(ss, msk, 64);
    if (lane == 0) out[row] = ss;
}

// ===========================================================================
// 8-wave 256-tile counted-vmcnt pipeline (T3+T4+T5). 512 threads, 3 LDS bufs.
// ===========================================================================
#define EIGHT_PROLOG(XPTR, YPTR)                                               \
    const int tid = threadIdx.x, lane = tid & 63, wid = tid >> 6;              \
    const int wr = wid >> 2, wc = wid & 3;                                     \
    const int hi = lane >> 4, lo = lane & 15;                                  \
    const int fsw = ((hi ^ ((lo >> 1) & 3)) << 3);                             \
    const int KT = D >> 5, KTm = KT - 1;                                       \
    const int NIT = (chunkCols >> 8) << 5 >> 1;                                \
    const size_t o128 = (size_t)128 * D;                                       \
    const ushort* pa = stage_ptr(XPTR, D, rbase, tid);                         \
    const ushort* pb = stage_ptr(YPTR, D, c0, tid);

__device__ inline void issue8(ushort* Lbuf, const ushort* qa, const ushort* qb,
                              size_t o128, int wid)
{
    ushort* A0 = Lbuf + (wid << 9);
    ushort* B0 = Lbuf + 8192 + (wid << 9);
    __builtin_amdgcn_global_load_lds((g_void*)qa,          (lds_void*)A0,          16, 0, 0);
    __builtin_amdgcn_global_load_lds((g_void*)(qa + o128), (lds_void*)(A0 + 4096), 16, 0, 0);
    __builtin_amdgcn_global_load_lds((g_void*)qb,          (lds_void*)B0,          16, 0, 0);
    __builtin_amdgcn_global_load_lds((g_void*)(qb + o128), (lds_void*)(B0 + 4096), 16, 0, 0);
}

// ---------------------------------------------------------------------------
// sim, 8-wave: per-row exp-sums + per-col exp-sums of (X Y^T)/0.07
// ---------------------------------------------------------------------------
__global__ __launch_bounds__(512, 2) void k_sim8(
    const ushort* __restrict__ X, const ushort* __restrict__ Y,
    float* __restrict__ pl, float* __restrict__ colsum,
    int Ntot, int D, int chunkCols)
{
    __shared__ __align__(16) ushort L3[3][16384];
    const int rbase = blockIdx.x * 256;
    const int c0 = blockIdx.y * chunkCols;
    const float inv_t = 1.0f / 0.07f;
    EIGHT_PROLOG(X, Y)

    f32x4 acc[8][4];
    float Ls[32];
#pragma unroll
    for (int m = 0; m < 8; ++m)
#pragma unroll
        for (int n = 0; n < 4; ++n)
#pragma unroll
            for (int j = 0; j < 4; ++j) acc[m][n][j] = 0.f;
#pragma unroll
    for (int i = 0; i < 32; ++i) Ls[i] = 0.f;

    issue8(&L3[0][0], pa, pb, o128, wid);
    pa += 32; pb += 32;
    issue8(&L3[1][0], pa, pb, o128, wid);
    if ((1 & KTm) == KTm) { pa -= (D - 32); pb += (size_t)256 * D - (D - 32); }
    else { pa += 32; pb += 32; }

    int ibuf = 0, sbuf = 2, kk = 0, tcol = 0;
    for (int it = 0; it < NIT; ++it) {
        const int s = it + 2;
        if (s < NIT) {
            issue8(&L3[sbuf][0], pa, pb, o128, wid);
            if ((s & KTm) == KTm) { pa -= (D - 32); pb += (size_t)256 * D - (D - 32); }
            else { pa += 32; pb += 32; }
            if (++sbuf == 3) sbuf = 0;
            asm volatile("s_waitcnt vmcnt(8)" ::: "memory");
        } else if (it + 1 < NIT) {
            asm volatile("s_waitcnt vmcnt(4)" ::: "memory");
        } else {
            asm volatile("s_waitcnt vmcnt(0)" ::: "memory");
        }
        __builtin_amdgcn_sched_barrier(0);
        __builtin_amdgcn_s_barrier();

        const ushort* Ab = &L3[ibuf][0];
        const ushort* Bb = &L3[ibuf][8192];
        s8bf bfr[4];
#pragma unroll
        for (int n = 0; n < 4; ++n)
            bfr[n] = *(const s8bf*)(Bb + (wc * 64 + n * 16 + lo) * 32 + fsw);
        __builtin_amdgcn_s_setprio(1);
#pragma unroll
        for (int m = 0; m < 8; ++m) {
            s8bf a = *(const s8bf*)(Ab + (wr * 128 + m * 16 + lo) * 32 + fsw);
#pragma unroll
            for (int n = 0; n < 4; ++n)
                acc[m][n] = __builtin_amdgcn_mfma_f32_16x16x32_bf16(a, bfr[n], acc[m][n], 0, 0, 0);
        }
        __builtin_amdgcn_s_setprio(0);
        __builtin_amdgcn_s_barrier();
        if (++ibuf == 3) ibuf = 0;

        if (++kk == KT) {
            kk = 0;
            const int cbase = c0 + tcol * 256 + wc * 64;
            float csum[4] = {0.f, 0.f, 0.f, 0.f};
#pragma unroll
            for (int m = 0; m < 8; ++m)
#pragma unroll
                for (int j = 0; j < 4; ++j) {
                    const int i = m * 4 + j;
#pragma unroll
                    for (int n = 0; n < 4; ++n) {
                        float e = __expf(acc[m][n][j] * inv_t);
                        Ls[i] += e;
                        csum[n] += e;
                        acc[m][n][j] = 0.f;
                    }
                }
#pragma unroll
            for (int n = 0; n < 4; ++n) {
                float cs = csum[n];
                cs += __shfl_xor(cs, 16, 64);
                cs += __shfl_xor(cs, 32, 64);
                if (hi == 0) atomicAdd(&colsum[cbase + n * 16 + lo], cs);
            }
            ++tcol;
        }
    }
#pragma unroll
    for (int i = 0; i < 32; ++i) {
#pragma unroll
        for (int msk = 1; msk < 16; msk <<= 1)
            Ls[i] += __shfl_xor(Ls[i], msk, 64);
    }
    if (lo == 0) {
        const int slot = blockIdx.y * 4 + wc;
#pragma unroll
        for (int m = 0; m < 8; ++m)
#pragma unroll
            for (int j = 0; j < 4; ++j) {
                int row = rbase + wr * 128 + m * 16 + hi * 4 + j;
                pl[(size_t)slot * Ntot + row] = Ls[m * 4 + j];
            }
    }
}

// ---------------------------------------------------------------------------
// dist, 8-wave: GEMM -> e=exp(-5d) -> PACKED bf16 store.
// cn chunk (chunkCols==1024) staged in LDS at kernel start: the epilogue then
// issues NO global loads, so the compiler's cn-wait no longer drains the
// prefetch queue at every col-tile boundary.
// Layout: within each 64-col block, store position pc = lo*4 + n holds the
// value for true column c = n*16 + lo  (involution decoded by consumers).
// ---------------------------------------------------------------------------
__global__ __launch_bounds__(512, 2) void k_dist8(
    const ushort* __restrict__ Za, const ushort* __restrict__ Zb,
    const ushort* __restrict__ CB, const float* __restrict__ cn,
    ushort* __restrict__ expm_a, ushort* __restrict__ expm_b,
    int Ntot, int Ktot, int D, int chunkCols)
{
    __shared__ __align__(16) ushort L3[3][16384];
    __shared__ float cnLds[1024];
    const ushort* Z = blockIdx.z ? Zb : Za;
    ushort* expm = blockIdx.z ? expm_b : expm_a;
    const int rbase = blockIdx.x * 256;
    const int c0 = blockIdx.y * chunkCols;
    EIGHT_PROLOG(Z, CB)

    // stage cn chunk into LDS (read-only afterwards; barrier-synced)
    cnLds[tid]       = 1.0f + cn[c0 + tid];
    cnLds[tid + 512] = 1.0f + cn[c0 + tid + 512];
    __syncthreads();

    f32x4 acc[8][4];
#pragma unroll
    for (int m = 0; m < 8; ++m)
#pragma unroll
        for (int n = 0; n < 4; ++n)
#pragma unroll
            for (int j = 0; j < 4; ++j) acc[m][n][j] = 0.f;

    issue8(&L3[0][0], pa, pb, o128, wid);
    pa += 32; pb += 32;
    issue8(&L3[1][0], pa, pb, o128, wid);
    if ((1 & KTm) == KTm) { pa -= (D - 32); pb += (size_t)256 * D - (D - 32); }
    else { pa += 32; pb += 32; }

    int ibuf = 0, sbuf = 2, kk = 0, tcol = 0;
    for (int it = 0; it < NIT; ++it) {
        const int s = it + 2;
        if (s < NIT) {
            issue8(&L3[sbuf][0], pa, pb, o128, wid);
            if ((s & KTm) == KTm) { pa -= (D - 32); pb += (size_t)256 * D - (D - 32); }
            else { pa += 32; pb += 32; }
            if (++sbuf == 3) sbuf = 0;
            asm volatile("s_waitcnt vmcnt(8)" ::: "memory");
        } else if (it + 1 < NIT) {
            asm volatile("s_waitcnt vmcnt(4)" ::: "memory");
        } else {
            asm volatile("s_waitcnt vmcnt(0)" ::: "memory");
        }
        __builtin_amdgcn_sched_barrier(0);
        __builtin_amdgcn_s_barrier();

        const ushort* Ab = &L3[ibuf][0];
        const ushort* Bb = &L3[ibuf][8192];
        s8bf bfr[4];
#pragma unroll
        for (int n = 0; n < 4; ++n)
            bfr[n] = *(const s8bf*)(Bb + (wc * 64 + n * 16 + lo) * 32 + fsw);
        __builtin_amdgcn_s_setprio(1);
#pragma unroll
        for (int m = 0; m < 8; ++m) {
            s8bf a = *(const s8bf*)(Ab + (wr * 128 + m * 16 + lo) * 32 + fsw);
#pragma unroll
            for (int n = 0; n < 4; ++n)
                acc[m][n] = __builtin_amdgcn_mfma_f32_16x16x32_bf16(a, bfr[n], acc[m][n], 0, 0, 0);
        }
        __builtin_amdgcn_s_setprio(0);
        __builtin_amdgcn_s_barrier();
        if (++ibuf == 3) ibuf = 0;

        if (++kk == KT) {
            kk = 0;
            const int cb0 = tcol * 256 + wc * 64;      // within-chunk (LDS idx)
            const int cbase = c0 + cb0;                // global col base
            float cnv[4];
#pragma unroll
            for (int n = 0; n < 4; ++n) cnv[n] = cnLds[cb0 + n * 16 + lo];
#pragma unroll
            for (int m = 0; m < 8; ++m)
#pragma unroll
                for (int j = 0; j < 4; ++j) {
                    const int row = rbase + wr * 128 + m * 16 + hi * 4 + j;
                    ushort4 ev;
                    {
                        float d0 = sqrtf(fmaxf(cnv[0] - 2.0f * acc[m][0][j], 0.f));
                        float d1 = sqrtf(fmaxf(cnv[1] - 2.0f * acc[m][1][j], 0.f));
                        float d2 = sqrtf(fmaxf(cnv[2] - 2.0f * acc[m][2][j], 0.f));
                        float d3 = sqrtf(fmaxf(cnv[3] - 2.0f * acc[m][3][j], 0.f));
                        ev.x = f2bf_fast(__expf(-5.0f * d0));
                        ev.y = f2bf_fast(__expf(-5.0f * d1));
                        ev.z = f2bf_fast(__expf(-5.0f * d2));
                        ev.w = f2bf_fast(__expf(-5.0f * d3));
                    }
                    *(ushort4*)(expm + (size_t)row * Ktot + cbase + lo * 4) = ev;
                    acc[m][0][j] = 0.f; acc[m][1][j] = 0.f;
                    acc[m][2][j] = 0.f; acc[m][3][j] = 0.f;
                }
            ++tcol;
        }
    }
}

// ---------------------------------------------------------------------------
// row stats from PERMUTED expm: per-row sum -> log L, 1/L; argmax -> argmin d.
// true col for permuted offset o within its 64-block: (o&3)*16 + (o>>2).
// ---------------------------------------------------------------------------
__global__ __launch_bounds__(256) void k_row_stats(
    const ushort* __restrict__ expm_a, const ushort* __restrict__ expm_b,
    int* __restrict__ idx_a, float* __restrict__ lse_a, float* __restrict__ inv_a,
    int* __restrict__ idx_b, float* __restrict__ lse_b, float* __restrict__ inv_b,
    int Ktot)
{
    const int z = blockIdx.y;
    const ushort* expm = z ? expm_b : expm_a;
    int* idx = z ? idx_b : idx_a;
    float* lse = z ? lse_b : lse_a;
    float* inv = z ? inv_b : inv_a;
    const int lane = threadIdx.x & 63, wid = threadIdx.x >> 6;
    const int row = blockIdx.x * 4 + wid;
    const uint4* p = (const uint4*)(expm + (size_t)row * Ktot);
    const int nf8 = Ktot >> 3;
    float s = 0.f, best = -1.f;
    int bc = 0x7FFFFFFF;
    for (int f = lane; f < nf8; f += 64) {
        uint4 u = p[f];
        const unsigned* w = (const unsigned*)&u;
        const int kp0 = f << 3;
        const int blk = kp0 & ~63;
#pragma unroll
        for (int q = 0; q < 4; ++q) {
            float2 e = bf2x2(w[q]);
            const int o0 = (kp0 & 63) + 2 * q;
            const int c0t = blk + ((o0 & 3) << 4) + (o0 >> 2);
            const int o1 = o0 + 1;
            const int c1t = blk + ((o1 & 3) << 4) + (o1 >> 2);
            s += e.x + e.y;
            if (e.x > best || (e.x == best && c0t < bc)) { best = e.x; bc = c0t; }
            if (e.y > best || (e.y == best && c1t < bc)) { best = e.y; bc = c1t; }
        }
    }
#pragma unroll
    for (int msk = 1; msk < 64; msk <<= 1) {
        float ob = __shfl_xor(best, msk, 64);
        int   ok = __shfl_xor(bc, msk, 64);
        s += __shfl_xor(s, msk, 64);
        if (ob > best || (ob == best && ok < bc)) { best = ob; bc = ok; }
    }
    if (lane == 0) {
        idx[row] = bc;
        lse[row] = __logf(s);
        inv[row] = 1.0f / s;
    }
}

// ---------------------------------------------------------------------------
// avg stream over PERMUTED expm: thread's 4 consecutive permuted positions map
// to true columns j0 + {0,16,32,48}, j0 = blk + ((pc&63)>>2).
// ---------------------------------------------------------------------------
__global__ __launch_bounds__(256) void k_avg_stream(
    const ushort* __restrict__ expm_a, const ushort* __restrict__ expm_b,
    const float* __restrict__ inv_a, const float* __restrict__ inv_b,
    float* __restrict__ avg_a, float* __restrict__ avg_b,
    int Ktot, int rows)
{
    const int z = blockIdx.z;
    const ushort* expm = z ? expm_b : expm_a;
    const float* invL = z ? inv_b : inv_a;
    float* avg = z ? avg_b : avg_a;
    const int pc = blockIdx.x * 1024 + threadIdx.x * 4;
    const int j0 = (pc & ~63) + ((pc & 63) >> 2);
    const int r0 = blockIdx.y * rows;
    float4 s = {0.f, 0.f, 0.f, 0.f};
    for (int r = r0; r < r0 + rows; ++r) {
        float il = invL[r];
        uint2 u = *(const uint2*)(expm + (size_t)r * Ktot + pc);
        float2 e0 = bf2x2(u.x);
        float2 e1 = bf2x2(u.y);
        s.x = fmaf(e0.x, il, s.x);
        s.y = fmaf(e0.y, il, s.y);
        s.z = fmaf(e1.x, il, s.z);
        s.w = fmaf(e1.y, il, s.w);
    }
    atomicAdd(&avg[j0 +  0], s.x);
    atomicAdd(&avg[j0 + 16], s.y);
    atomicAdd(&avg[j0 + 32], s.z);
    atomicAdd(&avg[j0 + 48], s.w);
}

// ---------------------------------------------------------------------------
// FALLBACK path (ws too small): 256-thr dist1 with slots + dist2 recompute
// ---------------------------------------------------------------------------
__global__ __launch_bounds__(256) void k_mfma_dist1_noexp(
    const ushort* __restrict__ Za, const ushort* __restrict__ Zb,
    const ushort* __restrict__ CB,
    const float* __restrict__ cn, float* __restrict__ pd,
    float* __restrict__ pls, int* __restrict__ pib,
    int Ntot, int D, int chunkCols)
{
    DBUF_DECL;
    const int z = blockIdx.z;
    const ushort* Z = z ? Zb : Za;
    const int tid = threadIdx.x, lane = tid & 63, wid = tid >> 6;
    const int wr = wid >> 1, wc = wid & 1;
    const int rbase = blockIdx.x * 128;
    const int c0 = blockIdx.y * chunkCols;
    const int hi = lane >> 4, lo = lane & 15;
    const int KS = D >> 5, TILES = chunkCols >> 7;
    const size_t o64 = (size_t)64 * D;
    const ptrdiff_t dWrapA = -(ptrdiff_t)(D - 32);
    const ptrdiff_t dWrapB = (ptrdiff_t)128 * D - (ptrdiff_t)(D - 32);

    float bd[16], ls[16]; int bi[16];
#pragma unroll
    for (int i = 0; i < 16; ++i) { bd[i] = FLT_MAX; ls[i] = 0.f; bi[i] = 0; }

    const ushort* pa = stage_ptr(Z, D, rbase, tid);
    const ushort* pb = stage_ptr(CB, D, c0, tid);
    stage_issue2(pa, pb, o64, o64, AS(0), BS(0), tid);
    __syncthreads();
    int phase = 0;
    for (int t = 0; t < TILES; ++t) {
        f32x4 acc[4][4];
#pragma unroll
        for (int m = 0; m < 4; ++m)
#pragma unroll
            for (int n = 0; n < 4; ++n)
#pragma unroll
                for (int j = 0; j < 4; ++j) acc[m][n][j] = 0.f;
        for (int ks = 0; ks < KS; ++ks) {
            const bool wrap = (ks + 1 == KS);
            pa += wrap ? dWrapA : 32;
            pb += wrap ? dWrapB : 32;
            if (!(wrap && t + 1 == TILES))
                stage_issue2(pa, pb, o64, o64, AS(phase ^ 1), BS(phase ^ 1), tid);
            mma_tile(AS(phase), BS(phase), wr, wc, lane, acc);
            __syncthreads();
            phase ^= 1;
        }
        const int cbase = c0 + (t << 7) + wc * 64;
        float cnv[4]; int cix[4];
#pragma unroll
        for (int n = 0; n < 4; ++n) {
            cix[n] = cbase + n * 16 + lo;
            cnv[n] = cn[cix[n]];
        }
#pragma unroll
        for (int m = 0; m < 4; ++m)
#pragma unroll
            for (int j = 0; j < 4; ++j) {
                const int i = m * 4 + j;
#pragma unroll
                for (int n = 0; n < 4; ++n) {
                    float d = sqrtf(fmaxf(1.0f + cnv[n] - 2.0f * acc[m][n][j], 0.f));
                    if (d < bd[i]) { bd[i] = d; bi[i] = cix[n]; }
                    ls[i] += __expf(-5.0f * d);
                }
            }
    }
#pragma unroll
    for (int i = 0; i < 16; ++i) {
#pragma unroll
        for (int msk = 1; msk < 16; msk <<= 1) {
            float od = __shfl_xor(bd[i], msk, 64);
            int   oi = __shfl_xor(bi[i], msk, 64);
            ls[i] += __shfl_xor(ls[i], msk, 64);
            if (od < bd[i] || (od == bd[i] && oi < bi[i])) { bd[i] = od; bi[i] = oi; }
        }
    }
    if (lo == 0) {
        const int slot = (z * gridDim.y + blockIdx.y) * 2 + wc;
#pragma unroll
        for (int m = 0; m < 4; ++m)
#pragma unroll
            for (int j = 0; j < 4; ++j) {
                int row = rbase + wr * 64 + m * 16 + hi * 4 + j;
                pd [(size_t)slot * Ntot + row] = bd[m * 4 + j];
                pls[(size_t)slot * Ntot + row] = ls[m * 4 + j];
                pib[(size_t)slot * Ntot + row] = bi[m * 4 + j];
            }
    }
}

__global__ __launch_bounds__(256) void k_dist1_reduce2(
    const float* __restrict__ pd, const float* __restrict__ pls,
    const int* __restrict__ pib,
    int* __restrict__ idx_a, float* __restrict__ lse_a, float* __restrict__ inv_a,
    int* __restrict__ idx_b, float* __restrict__ lse_b, float* __restrict__ inv_b,
    int Ntot, int slots)
{
    const int z = blockIdx.y;
    int row = blockIdx.x * 256 + threadIdx.x;
    if (row >= Ntot) return;
    const float* pdz = pd + (size_t)z * slots * Ntot;
    const float* plz = pls + (size_t)z * slots * Ntot;
    const int*   piz = pib + (size_t)z * slots * Ntot;
    float bd = FLT_MAX; int bi = 0;
    float L = 0.f;
    for (int s = 0; s < slots; ++s) {
        float d = pdz[(size_t)s * Ntot + row];
        int   i = piz[(size_t)s * Ntot + row];
        if (d < bd || (d == bd && i < bi)) { bd = d; bi = i; }
        L += plz[(size_t)s * Ntot + row];
    }
    if (z) { idx_b[row] = bi; lse_b[row] = __logf(L); inv_b[row] = 1.0f / L; }
    else   { idx_a[row] = bi; lse_a[row] = __logf(L); inv_a[row] = 1.0f / L; }
}

__global__ __launch_bounds__(256) void k_mfma_dist2(
    const ushort* __restrict__ Za, const ushort* __restrict__ Zb,
    const ushort* __restrict__ CB, const float* __restrict__ cn,
    const float* __restrict__ lse_a, const float* __restrict__ lse_b,
    float* __restrict__ avg_a, float* __restrict__ avg_b,
    int Ntot, int D, int chunkCols)
{
    DBUF_DECL;
    const ushort* Z = blockIdx.z ? Zb : Za;
    const float* lse = blockIdx.z ? lse_b : lse_a;
    float* avg = blockIdx.z ? avg_b : avg_a;
    const int tid = threadIdx.x, lane = tid & 63, wid = tid >> 6;
    const int wr = wid >> 1, wc = wid & 1;
    const int rbase = blockIdx.x * 128;
    const int c0 = blockIdx.y * chunkCols;
    const int hi = lane >> 4, lo = lane & 15;
    const int KS = D >> 5, TILES = chunkCols >> 7;
    const size_t o64 = (size_t)64 * D;
    const ptrdiff_t dWrapA = -(ptrdiff_t)(D - 32);
    const ptrdiff_t dWrapB = (ptrdiff_t)128 * D - (ptrdiff_t)(D - 32);

    float lr[16];
#pragma unroll
    for (int m = 0; m < 4; ++m)
#pragma unroll
        for (int j = 0; j < 4; ++j)
            lr[m * 4 + j] = lse[rbase + wr * 64 + m * 16 + hi * 4 + j];

    const ushort* pa = stage_ptr(Z, D, rbase, tid);
    const ushort* pb = stage_ptr(CB, D, c0, tid);
    stage_issue2(pa, pb, o64, o64, AS(0), BS(0), tid);
    __syncthreads();
    int phase = 0;
    for (int t = 0; t < TILES; ++t) {
        f32x4 acc[4][4];
#pragma unroll
        for (int m = 0; m < 4; ++m)
#pragma unroll
            for (int n = 0; n < 4; ++n)
#pragma unroll
                for (int j = 0; j < 4; ++j) acc[m][n][j] = 0.f;
        for (int ks = 0; ks < KS; ++ks) {
            const bool wrap = (ks + 1 == KS);
            pa += wrap ? dWrapA : 32;
            pb += wrap ? dWrapB : 32;
            if (!(wrap && t + 1 == TILES))
                stage_issue2(pa, pb, o64, o64, AS(phase ^ 1), BS(phase ^ 1), tid);
            mma_tile(AS(phase), BS(phase), wr, wc, lane, acc);
            __syncthreads();
            phase ^= 1;
        }
        const int cbase = c0 + (t << 7) + wc * 64;
        float cnv[4];
#pragma unroll
        for (int n = 0; n < 4; ++n) cnv[n] = cn[cbase + n * 16 + lo];
        float colsum[4] = {0.f, 0.f, 0.f, 0.f};
#pragma unroll
        for (int m = 0; m < 4; ++m)
#pragma unroll
            for (int j = 0; j < 4; ++j) {
                const int i = m * 4 + j;
#pragma unroll
                for (int n = 0; n < 4; ++n) {
                    float d = sqrtf(fmaxf(1.0f + cnv[n] - 2.0f * acc[m][n][j], 0.f));
                    colsum[n] += __expf(-5.0f * d - lr[i]);
                }
            }
#pragma unroll
        for (int n = 0; n < 4; ++n) {
            float cs = colsum[n];
            cs += __shfl_xor(cs, 16, 64);
            cs += __shfl_xor(cs, 32, 64);
            if (hi == 0) atomicAdd(&avg[cbase + n * 16 + lo], cs);
        }
    }
}

__global__ __launch_bounds__(256) void k_sum_log_reduce(
    const float* __restrict__ pl, float* __restrict__ out, int Ntot, int slots)
{
    int row = blockIdx.x * 256 + threadIdx.x;
    if (row >= Ntot) return;
    float L = 0.f;
    for (int s = 0; s < slots; ++s)
        L += pl[(size_t)s * Ntot + row];
    out[row] = __logf(L);
}

__global__ __launch_bounds__(256) void k_log_inplace(
    const float* __restrict__ src, float* __restrict__ dst, int n)
{
    int i = blockIdx.x * 256 + threadIdx.x;
    if (i < n) dst[i] = __logf(src[i]);
}

// ---------------------------------------------------------------------------
// rec/match/diag on bf16 inputs: linear decomposition, 6 atomics/block.
// ---------------------------------------------------------------------------
__global__ __launch_bounds__(256) void k_rec_match(
    const ushort* __restrict__ za, const ushort* __restrict__ zb,
    const ushort* __restrict__ cbk,
    const int* __restrict__ idx_a, const int* __restrict__ idx_b,
    const float* __restrict__ lse_ab, const float* __restrict__ lse_ba,
    float* __restrict__ acc, int N, int D)
{
    const int tid = threadIdx.x, lane = tid & 63, wid = tid >> 6;
    const int gw = blockIdx.x * 4 + wid;
    const int nw = gridDim.x * 4;
    const int nf8 = D >> 3;
    float pa = 0.f, pb = 0.f, pdot = 0.f;
    for (int row = gw; row < N; row += nw) {
        const int ia = idx_a[row], ib = idx_b[row];
        const uint4* pza = (const uint4*)(za + (size_t)row * D);
        const uint4* pzb = (const uint4*)(zb + (size_t)row * D);
        const uint4* pca = (const uint4*)(cbk + (size_t)ia * D);
        const uint4* pcb = (const uint4*)(cbk + (size_t)ib * D);
        for (int f = lane; f < nf8; f += 64) {
            uint4 ua = pza[f], ub = pzb[f], uc = pca[f], ud = pcb[f];
            const unsigned int* wa = (const unsigned int*)&ua;
            const unsigned int* wb = (const unsigned int*)&ub;
            const unsigned int* wc2 = (const unsigned int*)&uc;
            const unsigned int* wd = (const unsigned int*)&ud;
#pragma unroll
            for (int q = 0; q < 4; ++q) {
                float2 va = bf2x2(wa[q]), vb = bf2x2(wb[q]);
                float2 ca = bf2x2(wc2[q]), cb = bf2x2(wd[q]);
                float dx = va.x - ca.x, dy = va.y - ca.y;
                pa += dx * dx + dy * dy;
                dx = vb.x - cb.x; dy = vb.y - cb.y;
                pb += dx * dx + dy * dy;
                pdot += va.x * vb.x + va.y * vb.y;
            }
        }
    }
    float slab = 0.f, slba = 0.f, smatch = 0.f;
    for (int r = blockIdx.x * 256 + tid; r < N; r += gridDim.x * 256) {
        slab += lse_ab[r];
        slba += lse_ba[r];
        if (idx_a[r] == idx_b[r]) smatch += 1.f;
    }
#pragma unroll
    for (int msk = 1; msk < 64; msk <<= 1) {
        pa += __shfl_xor(pa, msk, 64);
        pb += __shfl_xor(pb, msk, 64);
        pdot += __shfl_xor(pdot, msk, 64);
        slab += __shfl_xor(slab, msk, 64);
        slba += __shfl_xor(slba, msk, 64);
        smatch += __shfl_xor(smatch, msk, 64);
    }
    __shared__ float red[4][6];
    if (lane == 0) {
        red[wid][0] = pa; red[wid][1] = pb; red[wid][2] = slab;
        red[wid][3] = slba; red[wid][4] = smatch; red[wid][5] = pdot;
    }
    __syncthreads();
    if (tid < 6) {
        float s = red[0][tid] + red[1][tid] + red[2][tid] + red[3][tid];
        atomicAdd(&acc[tid], s);
    }
}

// ---------------------------------------------------------------------------
// Final combine (1 block).
// ---------------------------------------------------------------------------
__global__ __launch_bounds__(256) void k_finalize(
    const float* __restrict__ avg_a, const float* __restrict__ avg_b,
    const float* __restrict__ acc, float* __restrict__ out,
    int N, int D, int K)
{
    __shared__ float red[256];
    const int tid = threadIdx.x;
    const float invN = 1.0f / (float)N;
    float sa = 0.f, sb = 0.f;
    for (int k = tid; k < K; k += 256) {
        float va = avg_a[k] * invN;
        float vb = avg_b[k] * invN;
        sa += va * logf(va + 1e-8f);
        sb += vb * logf(vb + 1e-8f);
    }
    red[tid] = sa;
    __syncthreads();
    for (int s = 128; s > 0; s >>= 1) {
        if (tid < s) red[tid] += red[tid + s];
        __syncthreads();
    }
    float entA = -red[0];
    __syncthreads();
    red[tid] = sb;
    __syncthreads();
    for (int s = 128; s > 0; s >>= 1) {
        if (tid < s) red[tid] += red[tid + s];
        __syncthreads();
    }
    if (tid == 0) {
        float entB = -red[0];
        float nd = (float)N * (float)D;
        float rec = 1.25f * (acc[0] / nd + acc[1] / nd);
        float sdot = acc[5] / 0.07f;
        float cm  = 0.5f * ((acc[2] - sdot) + (acc[3] - sdot)) * invN;
        float div = 0.5f * (entA + entB);
        out[0] = rec + 0.5f * cm - 0.1f * div;
        out[1] = acc[4] * invN;
    }
}

// ---------------------------------------------------------------------------
extern "C" void kernel_launch(void* const* d_in, const int* in_sizes, int n_in,
                              void* d_out, int out_size, void* d_ws, size_t ws_size,
                              hipStream_t stream)
{
    const float* a   = (const float*)d_in[0];
    const float* b   = (const float*)d_in[1];
    const float* Wa  = (const float*)d_in[2];
    const float* ba  = (const float*)d_in[3];
    const float* Wb  = (const float*)d_in[4];
    const float* bb  = (const float*)d_in[5];
    const float* cbk = (const float*)d_in[6];

    const int D  = in_sizes[3];            // 512
    const int dA = in_sizes[2] / D;        // 1024
    const int dB = in_sizes[4] / D;        // 1024
    const int N  = in_sizes[0] / dA;       // 8192
    const int K  = in_sizes[6] / D;        // 4096

    char* w = (char*)d_ws;
    size_t off = 0;
    auto alloc = [&](size_t bytes) -> void* {
        void* p = w + off;
        off = (off + bytes + 255) & ~(size_t)255;
        return p;
    };
    float*  za     = (float*)alloc((size_t)N * D * 4);
    float*  zb     = (float*)alloc((size_t)N * D * 4);
    float*  cn     = (float*)alloc((size_t)K * 4);
    int*    idx_a  = (int*)  alloc((size_t)N * 4);
    int*    idx_b  = (int*)  alloc((size_t)N * 4);
    float*  lse_a  = (float*)alloc((size_t)N * 4);
    float*  lse_b  = (float*)alloc((size_t)N * 4);
    float*  inv_a  = (float*)alloc((size_t)N * 4);
    float*  inv_b  = (float*)alloc((size_t)N * 4);
    float*  lse_ab = (float*)alloc((size_t)N * 4);
    float*  lse_ba = (float*)alloc((size_t)N * 4);
    float*  avgreg = (float*)alloc(((size_t)2 * K + 8) * 4);
    float*  avg_a  = avgreg;
    float*  avg_b  = avgreg + K;
    float*  accb   = avgreg + 2 * K;
    ushort* Wa_bf  = (ushort*)alloc((size_t)D * dA * 2);
    ushort* Wb_bf  = (ushort*)alloc((size_t)D * dB * 2);
    ushort* cbk_bf = (ushort*)alloc((size_t)K * D * 2);
    ushort* regionA = (ushort*)alloc((size_t)N * dA * 2);
    ushort* a_bf  = regionA;
    ushort* za_bf = regionA;
    ushort* zb_bf = regionA + (size_t)N * D;
    ushort* regionB = (ushort*)alloc((size_t)N * dB * 2);
    ushort* b_bf   = regionB;
    float* pl     = (float*)regionB;               // 32*N
    float* pd     = pl  + (size_t)32 * N;          // 64*N (fallback)
    float* pls    = pd  + (size_t)64 * N;          // 64*N (fallback)
    int*   pib    = (int*)(pls + (size_t)64 * N);  // 64*N (fallback)
    float* colsum = (float*)(pib + (size_t)64 * N); // N
    if (off > ws_size) return;
    ushort* expm_a = (ushort*)alloc((size_t)N * K * 2);
    ushort* expm_b = (ushort*)alloc((size_t)N * K * 2);
    const bool useExp = (off <= ws_size);

    dim3 blk(256);
    dim3 blk8(512);

    // bf16 conversions
    k_cvt_bf16<<<1024, blk, 0, stream>>>(a,   a_bf,   (size_t)N * dA);
    k_cvt_bf16<<<1024, blk, 0, stream>>>(b,   b_bf,   (size_t)N * dB);
    k_cvt_bf16<<<256,  blk, 0, stream>>>(Wa,  Wa_bf,  (size_t)D * dA);
    k_cvt_bf16<<<256,  blk, 0, stream>>>(Wb,  Wb_bf,  (size_t)D * dB);
    k_cvt_bf16<<<512,  blk, 0, stream>>>(cbk, cbk_bf, (size_t)K * D);

    // projections (fused a/b)
    k_mfma_gemm_bias2<<<dim3(N / 128, D / 128, 2), blk, 0, stream>>>(
        a_bf, Wa_bf, ba, za, b_bf, Wb_bf, bb, zb, D, dA);

    // normalize both + codebook norms
    k_normalize2<<<dim3((N + 3) / 4, 2), blk, 0, stream>>>(za, za_bf, zb, zb_bf, N, D);
    k_rownorm2<<<dim3((K + 3) / 4), blk, 0, stream>>>(cbk, cn, K, D);
    hipMemsetAsync(avgreg, 0, ((size_t)2 * K + 8) * 4, stream);
    hipMemsetAsync(colsum, 0, (size_t)N * 4, stream);

    // distances
    if (useExp) {
        const int dchunk = 1024;                       // 4 col-tiles of 256
        k_dist8<<<dim3(N / 256, K / dchunk, 2), blk8, 0, stream>>>(
            za_bf, zb_bf, cbk_bf, cn, expm_a, expm_b, N, K, D, dchunk);
        k_row_stats<<<dim3(N / 4, 2), blk, 0, stream>>>(
            expm_a, expm_b, idx_a, lse_a, inv_a, idx_b, lse_b, inv_b, K);
        k_avg_stream<<<dim3(K / 1024, N / 64, 2), blk, 0, stream>>>(
            expm_a, expm_b, inv_a, inv_b, avg_a, avg_b, K, 64);
    } else {
        const int dchunk = 256, dcy = K / dchunk;
        dim3 dgrid(N / 128, dcy, 2);
        k_mfma_dist1_noexp<<<dgrid, blk, 0, stream>>>(
            za_bf, zb_bf, cbk_bf, cn, pd, pls, pib, N, D, dchunk);
        k_dist1_reduce2<<<dim3(N / 256, 2), blk, 0, stream>>>(
            pd, pls, pib, idx_a, lse_a, inv_a, idx_b, lse_b, inv_b, N, 2 * dcy);
        k_mfma_dist2<<<dgrid, blk, 0, stream>>>(
            za_bf, zb_bf, cbk_bf, cn, lse_a, lse_b, avg_a, avg_b, N, D, dchunk);
    }

    // contrastive: one 8-wave pass -> row exp-sums (pl slots) + col exp-sums
    const int schunk = 1024, scy = N / schunk;         // grid (32, 8) = 256 blocks
    k_sim8<<<dim3(N / 256, scy), blk8, 0, stream>>>(za_bf, zb_bf, pl, colsum, N, D, schunk);
    k_sum_log_reduce<<<N / 256, blk, 0, stream>>>(pl, lse_ab, N, 4 * scy);
    k_log_inplace<<<N / 256, blk, 0, stream>>>(colsum, lse_ba, N);

    // rec/match/diag + final combine
    k_rec_match<<<256, blk, 0, stream>>>(za_bf, zb_bf, cbk_bf, idx_a, idx_b, lse_ab, lse_ba, accb, N, D);
    k_finalize<<<1, blk, 0, stream>>>(avg_a, avg_b, accb, (float*)d_out, N, D, K);
}

// Round 15
// 333.038 us; speedup vs baseline: 1.0422x; 1.0422x over previous
//
#include <hip/hip_runtime.h>
#include <hip/hip_bf16.h>
#include <math.h>
#include <float.h>

typedef __attribute__((ext_vector_type(8))) short s8bf;
typedef __attribute__((ext_vector_type(4))) float f32x4;

typedef const __attribute__((address_space(1))) void g_void;
typedef __attribute__((address_space(3))) void lds_void;

__device__ inline ushort f2bf(float x) {
    unsigned int u = __float_as_uint(x);
    unsigned int r = (u + 0x7FFFu + ((u >> 16) & 1u)) >> 16;
    return (ushort)r;
}
__device__ inline ushort f2bf_fast(float x) {
    return (ushort)((__float_as_uint(x) + 0x8000u) >> 16);
}
__device__ inline float2 bf2x2(unsigned int u) {
    float2 r;
    r.x = __uint_as_float(u << 16);
    r.y = __uint_as_float(u & 0xFFFF0000u);
    return r;
}

// ---------------------------------------------------------------------------
// fp32 -> bf16 bulk convert
// ---------------------------------------------------------------------------
__global__ __launch_bounds__(256) void k_cvt_bf16(
    const float* __restrict__ src, ushort* __restrict__ dst, size_t n)
{
    size_t i = ((size_t)blockIdx.x * 256 + threadIdx.x) * 4;
    size_t stride = (size_t)gridDim.x * 256 * 4;
    for (; i < n; i += stride) {
        float4 v = *(const float4*)(src + i);
        ushort4 o;
        o.x = f2bf(v.x); o.y = f2bf(v.y); o.z = f2bf(v.z); o.w = f2bf(v.w);
        *(ushort4*)(dst + i) = o;
    }
}

// per-thread source pointer: row = tid>>2, 16B slot (tid&3) XOR-swizzled by row
__device__ inline const ushort* stage_ptr(const ushort* M, size_t ld, int ra, int tid)
{
    const int row  = tid >> 2;
    const int slot = tid & 3;
    const int scol = ((slot ^ ((row >> 1) & 3)) << 3);
    return M + (size_t)(ra + row) * ld + scol;
}

// ===========================================================================
// 256-thread, 128x128-tile 2-phase machinery (projection GEMM + fallback)
// ===========================================================================
__device__ inline void stage_issue2(const ushort* pa, const ushort* pb,
                                    size_t off64a, size_t off64b,
                                    ushort* As, ushort* Bs, int tid)
{
    const int wb = (tid >> 6) << 9;
    __builtin_amdgcn_global_load_lds((g_void*)pa,            (lds_void*)(As + wb),        16, 0, 0);
    __builtin_amdgcn_global_load_lds((g_void*)(pa + off64a), (lds_void*)(As + 2048 + wb), 16, 0, 0);
    __builtin_amdgcn_global_load_lds((g_void*)pb,            (lds_void*)(Bs + wb),        16, 0, 0);
    __builtin_amdgcn_global_load_lds((g_void*)(pb + off64b), (lds_void*)(Bs + 2048 + wb), 16, 0, 0);
}

__device__ inline void mma_tile(const ushort* As, const ushort* Bs,
                                int wr, int wc, int lane, f32x4 acc[4][4])
{
    const int hi = lane >> 4, lo = lane & 15;
    const int soff = ((hi ^ ((lo >> 1) & 3)) << 3);
    s8bf af[4], bfr[4];
#pragma unroll
    for (int m = 0; m < 4; ++m)
        af[m] = *(const s8bf*)(As + (wr * 64 + m * 16 + lo) * 32 + soff);
#pragma unroll
    for (int n = 0; n < 4; ++n)
        bfr[n] = *(const s8bf*)(Bs + (wc * 64 + n * 16 + lo) * 32 + soff);
#pragma unroll
    for (int m = 0; m < 4; ++m)
#pragma unroll
        for (int n = 0; n < 4; ++n)
            acc[m][n] = __builtin_amdgcn_mfma_f32_16x16x32_bf16(
                af[m], bfr[n], acc[m][n], 0, 0, 0);
}

#define DBUF_DECL  __shared__ __align__(16) ushort Lds[2][8192]
#define AS(p) (&Lds[p][0])
#define BS(p) (&Lds[p][4096])

// ---------------------------------------------------------------------------
// Fused projections: z=0 -> za = a@Wa^T+ba ; z=1 -> zb = b@Wb^T+bb
// ---------------------------------------------------------------------------
__global__ __launch_bounds__(256) void k_mfma_gemm_bias2(
    const ushort* __restrict__ Aa, const ushort* __restrict__ Wa,
    const float* __restrict__ ba, float* __restrict__ Ca,
    const ushort* __restrict__ Ab, const ushort* __restrict__ Wb,
    const float* __restrict__ bb, float* __restrict__ Cb,
    int Ncols, int Kd)
{
    DBUF_DECL;
    const int z = blockIdx.z;
    const ushort* A = z ? Ab : Aa;
    const ushort* W = z ? Wb : Wa;
    const float* bias = z ? bb : ba;
    float* C = z ? Cb : Ca;

    const int tid = threadIdx.x, lane = tid & 63, wid = tid >> 6;
    const int wr = wid >> 1, wc = wid & 1;
    const int rbase = blockIdx.x * 128, cbase = blockIdx.y * 128;
    const int hi = lane >> 4, lo = lane & 15;
    const int KS = Kd >> 5;
    const size_t o64 = (size_t)64 * Kd;

    f32x4 acc[4][4];
#pragma unroll
    for (int m = 0; m < 4; ++m)
#pragma unroll
        for (int n = 0; n < 4; ++n)
#pragma unroll
            for (int j = 0; j < 4; ++j) acc[m][n][j] = 0.f;

    const ushort* pa = stage_ptr(A, Kd, rbase, tid);
    const ushort* pb = stage_ptr(W, Kd, cbase, tid);
    stage_issue2(pa, pb, o64, o64, AS(0), BS(0), tid);
    __syncthreads();
    int phase = 0;
    for (int ks = 0; ks < KS; ++ks) {
        pa += 32; pb += 32;
        if (ks + 1 < KS)
            stage_issue2(pa, pb, o64, o64, AS(phase ^ 1), BS(phase ^ 1), tid);
        mma_tile(AS(phase), BS(phase), wr, wc, lane, acc);
        __syncthreads();
        phase ^= 1;
    }
#pragma unroll
    for (int n = 0; n < 4; ++n) {
        int col = cbase + wc * 64 + n * 16 + lo;
        float bv = bias[col];
#pragma unroll
        for (int m = 0; m < 4; ++m)
#pragma unroll
            for (int j = 0; j < 4; ++j) {
                int row = rbase + wr * 64 + m * 16 + hi * 4 + j;
                C[(size_t)row * Ncols + col] = acc[m][n][j] + bv;
            }
    }
}

// ---------------------------------------------------------------------------
// Row L2-normalize both za and zb (blockIdx.y picks), fp32 in -> bf16 out.
// ---------------------------------------------------------------------------
__global__ __launch_bounds__(256) void k_normalize2(
    const float* __restrict__ Za, ushort* __restrict__ Zab,
    const float* __restrict__ Zb, ushort* __restrict__ Zbb, int N, int D)
{
    const float* Z = blockIdx.y ? Zb : Za;
    ushort* Zo = blockIdx.y ? Zbb : Zab;
    const int lane = threadIdx.x & 63, wid = threadIdx.x >> 6;
    const int row = blockIdx.x * 4 + wid;
    if (row >= N) return;
    const float4* p = (const float4*)(Z + (size_t)row * D);
    const int nf4 = D >> 2;
    float ss = 0.f;
    for (int f = lane; f < nf4; f += 64) {
        float4 v = p[f];
        ss += v.x * v.x + v.y * v.y + v.z * v.z + v.w * v.w;
    }
#pragma unroll
    for (int msk = 1; msk < 64; msk <<= 1) ss += __shfl_xor(ss, msk, 64);
    float sc = 1.0f / fmaxf(sqrtf(ss), 1e-12f);
    ushort4* pb = (ushort4*)(Zo + (size_t)row * D);
    for (int f = lane; f < nf4; f += 64) {
        float4 v = p[f];
        ushort4 u;
        u.x = f2bf(v.x * sc); u.y = f2bf(v.y * sc);
        u.z = f2bf(v.z * sc); u.w = f2bf(v.w * sc);
        pb[f] = u;
    }
}

// ---------------------------------------------------------------------------
// Row sum-of-squares (codebook norms). Wave per row.
// ---------------------------------------------------------------------------
__global__ __launch_bounds__(256) void k_rownorm2(
    const float* __restrict__ X, float* __restrict__ out, int N, int D)
{
    const int lane = threadIdx.x & 63, wid = threadIdx.x >> 6;
    const int row = blockIdx.x * 4 + wid;
    if (row >= N) return;
    const float4* p = (const float4*)(X + (size_t)row * D);
    const int nf4 = D >> 2;
    float ss = 0.f;
    for (int f = lane; f < nf4; f += 64) {
        float4 v = p[f];
        ss += v.x * v.x + v.y * v.y + v.z * v.z + v.w * v.w;
    }
#pragma unroll
    for (int msk = 1; msk < 64; msk <<= 1) ss += __shfl_xor(ss, msk, 64);
    if (lane == 0) out[row] = ss;
}

// ===========================================================================
// 8-wave 256-tile counted-vmcnt pipeline (T3+T4+T5). 512 threads, 3 LDS bufs.
// ===========================================================================
#define EIGHT_PROLOG(XPTR, YPTR)                                               \
    const int tid = threadIdx.x, lane = tid & 63, wid = tid >> 6;              \
    const int wr = wid >> 2, wc = wid & 3;                                     \
    const int hi = lane >> 4, lo = lane & 15;                                  \
    const int fsw = ((hi ^ ((lo >> 1) & 3)) << 3);                             \
    const int KT = D >> 5, KTm = KT - 1;                                       \
    const int NIT = (chunkCols >> 8) << 5 >> 1;                                \
    const size_t o128 = (size_t)128 * D;                                       \
    const ushort* pa = stage_ptr(XPTR, D, rbase, tid);                         \
    const ushort* pb = stage_ptr(YPTR, D, c0, tid);

__device__ inline void issue8(ushort* Lbuf, const ushort* qa, const ushort* qb,
                              size_t o128, int wid)
{
    ushort* A0 = Lbuf + (wid << 9);
    ushort* B0 = Lbuf + 8192 + (wid << 9);
    __builtin_amdgcn_global_load_lds((g_void*)qa,          (lds_void*)A0,          16, 0, 0);
    __builtin_amdgcn_global_load_lds((g_void*)(qa + o128), (lds_void*)(A0 + 4096), 16, 0, 0);
    __builtin_amdgcn_global_load_lds((g_void*)qb,          (lds_void*)B0,          16, 0, 0);
    __builtin_amdgcn_global_load_lds((g_void*)(qb + o128), (lds_void*)(B0 + 4096), 16, 0, 0);
}

// ---------------------------------------------------------------------------
// sim, 8-wave: per-row exp-sums + per-col exp-sums of (X Y^T)/0.07
// ---------------------------------------------------------------------------
__global__ __launch_bounds__(512, 2) void k_sim8(
    const ushort* __restrict__ X, const ushort* __restrict__ Y,
    float* __restrict__ pl, float* __restrict__ colsum,
    int Ntot, int D, int chunkCols)
{
    __shared__ __align__(16) ushort L3[3][16384];
    const int rbase = blockIdx.x * 256;
    const int c0 = blockIdx.y * chunkCols;
    const float inv_t = 1.0f / 0.07f;
    EIGHT_PROLOG(X, Y)

    f32x4 acc[8][4];
    float Ls[32];
#pragma unroll
    for (int m = 0; m < 8; ++m)
#pragma unroll
        for (int n = 0; n < 4; ++n)
#pragma unroll
            for (int j = 0; j < 4; ++j) acc[m][n][j] = 0.f;
#pragma unroll
    for (int i = 0; i < 32; ++i) Ls[i] = 0.f;

    issue8(&L3[0][0], pa, pb, o128, wid);
    pa += 32; pb += 32;
    issue8(&L3[1][0], pa, pb, o128, wid);
    if ((1 & KTm) == KTm) { pa -= (D - 32); pb += (size_t)256 * D - (D - 32); }
    else { pa += 32; pb += 32; }

    int ibuf = 0, sbuf = 2, kk = 0, tcol = 0;
    for (int it = 0; it < NIT; ++it) {
        const int s = it + 2;
        if (s < NIT) {
            issue8(&L3[sbuf][0], pa, pb, o128, wid);
            if ((s & KTm) == KTm) { pa -= (D - 32); pb += (size_t)256 * D - (D - 32); }
            else { pa += 32; pb += 32; }
            if (++sbuf == 3) sbuf = 0;
            asm volatile("s_waitcnt vmcnt(8)" ::: "memory");
        } else if (it + 1 < NIT) {
            asm volatile("s_waitcnt vmcnt(4)" ::: "memory");
        } else {
            asm volatile("s_waitcnt vmcnt(0)" ::: "memory");
        }
        __builtin_amdgcn_sched_barrier(0);
        __builtin_amdgcn_s_barrier();

        const ushort* Ab = &L3[ibuf][0];
        const ushort* Bb = &L3[ibuf][8192];
        s8bf bfr[4];
#pragma unroll
        for (int n = 0; n < 4; ++n)
            bfr[n] = *(const s8bf*)(Bb + (wc * 64 + n * 16 + lo) * 32 + fsw);
        __builtin_amdgcn_s_setprio(1);
#pragma unroll
        for (int m = 0; m < 8; ++m) {
            s8bf a = *(const s8bf*)(Ab + (wr * 128 + m * 16 + lo) * 32 + fsw);
#pragma unroll
            for (int n = 0; n < 4; ++n)
                acc[m][n] = __builtin_amdgcn_mfma_f32_16x16x32_bf16(a, bfr[n], acc[m][n], 0, 0, 0);
        }
        __builtin_amdgcn_s_setprio(0);
        __builtin_amdgcn_s_barrier();
        if (++ibuf == 3) ibuf = 0;

        if (++kk == KT) {
            kk = 0;
            const int cbase = c0 + tcol * 256 + wc * 64;
            float csum[4] = {0.f, 0.f, 0.f, 0.f};
#pragma unroll
            for (int m = 0; m < 8; ++m)
#pragma unroll
                for (int j = 0; j < 4; ++j) {
                    const int i = m * 4 + j;
#pragma unroll
                    for (int n = 0; n < 4; ++n) {
                        float e = __expf(acc[m][n][j] * inv_t);
                        Ls[i] += e;
                        csum[n] += e;
                        acc[m][n][j] = 0.f;
                    }
                }
#pragma unroll
            for (int n = 0; n < 4; ++n) {
                float cs = csum[n];
                cs += __shfl_xor(cs, 16, 64);
                cs += __shfl_xor(cs, 32, 64);
                if (hi == 0) atomicAdd(&colsum[cbase + n * 16 + lo], cs);
            }
            ++tcol;
        }
    }
#pragma unroll
    for (int i = 0; i < 32; ++i) {
#pragma unroll
        for (int msk = 1; msk < 16; msk <<= 1)
            Ls[i] += __shfl_xor(Ls[i], msk, 64);
    }
    if (lo == 0) {
        const int slot = blockIdx.y * 4 + wc;
#pragma unroll
        for (int m = 0; m < 8; ++m)
#pragma unroll
            for (int j = 0; j < 4; ++j) {
                int row = rbase + wr * 128 + m * 16 + hi * 4 + j;
                pl[(size_t)slot * Ntot + row] = Ls[m * 4 + j];
            }
    }
}

// ---------------------------------------------------------------------------
// dist, 8-wave: GEMM -> e=exp(-5d) -> PACKED bf16 store.
// Layout: within each 64-col block, store position pc = lo*4 + n holds the
// value for true column c = n*16 + lo  (involution decoded by consumers).
// Gives one 8-byte ushort4 store per (m,j) instead of 4 scattered shorts.
// ---------------------------------------------------------------------------
__global__ __launch_bounds__(512, 2) void k_dist8(
    const ushort* __restrict__ Za, const ushort* __restrict__ Zb,
    const ushort* __restrict__ CB, const float* __restrict__ cn,
    ushort* __restrict__ expm_a, ushort* __restrict__ expm_b,
    int Ntot, int Ktot, int D, int chunkCols)
{
    __shared__ __align__(16) ushort L3[3][16384];
    const ushort* Z = blockIdx.z ? Zb : Za;
    ushort* expm = blockIdx.z ? expm_b : expm_a;
    const int rbase = blockIdx.x * 256;
    const int c0 = blockIdx.y * chunkCols;
    EIGHT_PROLOG(Z, CB)

    f32x4 acc[8][4];
#pragma unroll
    for (int m = 0; m < 8; ++m)
#pragma unroll
        for (int n = 0; n < 4; ++n)
#pragma unroll
            for (int j = 0; j < 4; ++j) acc[m][n][j] = 0.f;

    issue8(&L3[0][0], pa, pb, o128, wid);
    pa += 32; pb += 32;
    issue8(&L3[1][0], pa, pb, o128, wid);
    if ((1 & KTm) == KTm) { pa -= (D - 32); pb += (size_t)256 * D - (D - 32); }
    else { pa += 32; pb += 32; }

    int ibuf = 0, sbuf = 2, kk = 0, tcol = 0;
    for (int it = 0; it < NIT; ++it) {
        const int s = it + 2;
        if (s < NIT) {
            issue8(&L3[sbuf][0], pa, pb, o128, wid);
            if ((s & KTm) == KTm) { pa -= (D - 32); pb += (size_t)256 * D - (D - 32); }
            else { pa += 32; pb += 32; }
            if (++sbuf == 3) sbuf = 0;
            asm volatile("s_waitcnt vmcnt(8)" ::: "memory");
        } else if (it + 1 < NIT) {
            asm volatile("s_waitcnt vmcnt(4)" ::: "memory");
        } else {
            asm volatile("s_waitcnt vmcnt(0)" ::: "memory");
        }
        __builtin_amdgcn_sched_barrier(0);
        __builtin_amdgcn_s_barrier();

        const ushort* Ab = &L3[ibuf][0];
        const ushort* Bb = &L3[ibuf][8192];
        s8bf bfr[4];
#pragma unroll
        for (int n = 0; n < 4; ++n)
            bfr[n] = *(const s8bf*)(Bb + (wc * 64 + n * 16 + lo) * 32 + fsw);
        __builtin_amdgcn_s_setprio(1);
#pragma unroll
        for (int m = 0; m < 8; ++m) {
            s8bf a = *(const s8bf*)(Ab + (wr * 128 + m * 16 + lo) * 32 + fsw);
#pragma unroll
            for (int n = 0; n < 4; ++n)
                acc[m][n] = __builtin_amdgcn_mfma_f32_16x16x32_bf16(a, bfr[n], acc[m][n], 0, 0, 0);
        }
        __builtin_amdgcn_s_setprio(0);
        __builtin_amdgcn_s_barrier();
        if (++ibuf == 3) ibuf = 0;

        if (++kk == KT) {
            kk = 0;
            const int cbase = c0 + tcol * 256 + wc * 64;
            float cnv[4];
#pragma unroll
            for (int n = 0; n < 4; ++n) cnv[n] = 1.0f + cn[cbase + n * 16 + lo];
#pragma unroll
            for (int m = 0; m < 8; ++m)
#pragma unroll
                for (int j = 0; j < 4; ++j) {
                    const int row = rbase + wr * 128 + m * 16 + hi * 4 + j;
                    ushort4 ev;
                    {
                        float d0 = sqrtf(fmaxf(cnv[0] - 2.0f * acc[m][0][j], 0.f));
                        float d1 = sqrtf(fmaxf(cnv[1] - 2.0f * acc[m][1][j], 0.f));
                        float d2 = sqrtf(fmaxf(cnv[2] - 2.0f * acc[m][2][j], 0.f));
                        float d3 = sqrtf(fmaxf(cnv[3] - 2.0f * acc[m][3][j], 0.f));
                        ev.x = f2bf_fast(__expf(-5.0f * d0));
                        ev.y = f2bf_fast(__expf(-5.0f * d1));
                        ev.z = f2bf_fast(__expf(-5.0f * d2));
                        ev.w = f2bf_fast(__expf(-5.0f * d3));
                    }
                    *(ushort4*)(expm + (size_t)row * Ktot + cbase + lo * 4) = ev;
                    acc[m][0][j] = 0.f; acc[m][1][j] = 0.f;
                    acc[m][2][j] = 0.f; acc[m][3][j] = 0.f;
                }
            ++tcol;
        }
    }
}

// ---------------------------------------------------------------------------
// row stats from PERMUTED expm: per-row sum -> log L, 1/L; argmax -> argmin d.
// true col for permuted offset o within its 64-block: (o&3)*16 + (o>>2).
// ---------------------------------------------------------------------------
__global__ __launch_bounds__(256) void k_row_stats(
    const ushort* __restrict__ expm_a, const ushort* __restrict__ expm_b,
    int* __restrict__ idx_a, float* __restrict__ lse_a, float* __restrict__ inv_a,
    int* __restrict__ idx_b, float* __restrict__ lse_b, float* __restrict__ inv_b,
    int Ktot)
{
    const int z = blockIdx.y;
    const ushort* expm = z ? expm_b : expm_a;
    int* idx = z ? idx_b : idx_a;
    float* lse = z ? lse_b : lse_a;
    float* inv = z ? inv_b : inv_a;
    const int lane = threadIdx.x & 63, wid = threadIdx.x >> 6;
    const int row = blockIdx.x * 4 + wid;
    const uint4* p = (const uint4*)(expm + (size_t)row * Ktot);
    const int nf8 = Ktot >> 3;
    float s = 0.f, best = -1.f;
    int bc = 0x7FFFFFFF;
    for (int f = lane; f < nf8; f += 64) {
        uint4 u = p[f];
        const unsigned* w = (const unsigned*)&u;
        const int kp0 = f << 3;
        const int blk = kp0 & ~63;
#pragma unroll
        for (int q = 0; q < 4; ++q) {
            float2 e = bf2x2(w[q]);
            const int o0 = (kp0 & 63) + 2 * q;
            const int c0t = blk + ((o0 & 3) << 4) + (o0 >> 2);
            const int o1 = o0 + 1;
            const int c1t = blk + ((o1 & 3) << 4) + (o1 >> 2);
            s += e.x + e.y;
            if (e.x > best || (e.x == best && c0t < bc)) { best = e.x; bc = c0t; }
            if (e.y > best || (e.y == best && c1t < bc)) { best = e.y; bc = c1t; }
        }
    }
#pragma unroll
    for (int msk = 1; msk < 64; msk <<= 1) {
        float ob = __shfl_xor(best, msk, 64);
        int   ok = __shfl_xor(bc, msk, 64);
        s += __shfl_xor(s, msk, 64);
        if (ob > best || (ob == best && ok < bc)) { best = ob; bc = ok; }
    }
    if (lane == 0) {
        idx[row] = bc;
        lse[row] = __logf(s);
        inv[row] = 1.0f / s;
    }
}

// ---------------------------------------------------------------------------
// avg stream over PERMUTED expm: thread's 4 consecutive permuted positions map
// to true columns j0 + {0,16,32,48}, j0 = blk + ((pc&63)>>2).
// ---------------------------------------------------------------------------
__global__ __launch_bounds__(256) void k_avg_stream(
    const ushort* __restrict__ expm_a, const ushort* __restrict__ expm_b,
    const float* __restrict__ inv_a, const float* __restrict__ inv_b,
    float* __restrict__ avg_a, float* __restrict__ avg_b,
    int Ktot, int rows)
{
    const int z = blockIdx.z;
    const ushort* expm = z ? expm_b : expm_a;
    const float* invL = z ? inv_b : inv_a;
    float* avg = z ? avg_b : avg_a;
    const int pc = blockIdx.x * 1024 + threadIdx.x * 4;
    const int j0 = (pc & ~63) + ((pc & 63) >> 2);
    const int r0 = blockIdx.y * rows;
    float4 s = {0.f, 0.f, 0.f, 0.f};
    for (int r = r0; r < r0 + rows; ++r) {
        float il = invL[r];
        uint2 u = *(const uint2*)(expm + (size_t)r * Ktot + pc);
        float2 e0 = bf2x2(u.x);
        float2 e1 = bf2x2(u.y);
        s.x = fmaf(e0.x, il, s.x);
        s.y = fmaf(e0.y, il, s.y);
        s.z = fmaf(e1.x, il, s.z);
        s.w = fmaf(e1.y, il, s.w);
    }
    atomicAdd(&avg[j0 +  0], s.x);
    atomicAdd(&avg[j0 + 16], s.y);
    atomicAdd(&avg[j0 + 32], s.z);
    atomicAdd(&avg[j0 + 48], s.w);
}

// ---------------------------------------------------------------------------
// FALLBACK path (ws too small): 256-thr dist1 with slots + dist2 recompute
// ---------------------------------------------------------------------------
__global__ __launch_bounds__(256) void k_mfma_dist1_noexp(
    const ushort* __restrict__ Za, const ushort* __restrict__ Zb,
    const ushort* __restrict__ CB,
    const float* __restrict__ cn, float* __restrict__ pd,
    float* __restrict__ pls, int* __restrict__ pib,
    int Ntot, int D, int chunkCols)
{
    DBUF_DECL;
    const int z = blockIdx.z;
    const ushort* Z = z ? Zb : Za;
    const int tid = threadIdx.x, lane = tid & 63, wid = tid >> 6;
    const int wr = wid >> 1, wc = wid & 1;
    const int rbase = blockIdx.x * 128;
    const int c0 = blockIdx.y * chunkCols;
    const int hi = lane >> 4, lo = lane & 15;
    const int KS = D >> 5, TILES = chunkCols >> 7;
    const size_t o64 = (size_t)64 * D;
    const ptrdiff_t dWrapA = -(ptrdiff_t)(D - 32);
    const ptrdiff_t dWrapB = (ptrdiff_t)128 * D - (ptrdiff_t)(D - 32);

    float bd[16], ls[16]; int bi[16];
#pragma unroll
    for (int i = 0; i < 16; ++i) { bd[i] = FLT_MAX; ls[i] = 0.f; bi[i] = 0; }

    const ushort* pa = stage_ptr(Z, D, rbase, tid);
    const ushort* pb = stage_ptr(CB, D, c0, tid);
    stage_issue2(pa, pb, o64, o64, AS(0), BS(0), tid);
    __syncthreads();
    int phase = 0;
    for (int t = 0; t < TILES; ++t) {
        f32x4 acc[4][4];
#pragma unroll
        for (int m = 0; m < 4; ++m)
#pragma unroll
            for (int n = 0; n < 4; ++n)
#pragma unroll
                for (int j = 0; j < 4; ++j) acc[m][n][j] = 0.f;
        for (int ks = 0; ks < KS; ++ks) {
            const bool wrap = (ks + 1 == KS);
            pa += wrap ? dWrapA : 32;
            pb += wrap ? dWrapB : 32;
            if (!(wrap && t + 1 == TILES))
                stage_issue2(pa, pb, o64, o64, AS(phase ^ 1), BS(phase ^ 1), tid);
            mma_tile(AS(phase), BS(phase), wr, wc, lane, acc);
            __syncthreads();
            phase ^= 1;
        }
        const int cbase = c0 + (t << 7) + wc * 64;
        float cnv[4]; int cix[4];
#pragma unroll
        for (int n = 0; n < 4; ++n) {
            cix[n] = cbase + n * 16 + lo;
            cnv[n] = cn[cix[n]];
        }
#pragma unroll
        for (int m = 0; m < 4; ++m)
#pragma unroll
            for (int j = 0; j < 4; ++j) {
                const int i = m * 4 + j;
#pragma unroll
                for (int n = 0; n < 4; ++n) {
                    float d = sqrtf(fmaxf(1.0f + cnv[n] - 2.0f * acc[m][n][j], 0.f));
                    if (d < bd[i]) { bd[i] = d; bi[i] = cix[n]; }
                    ls[i] += __expf(-5.0f * d);
                }
            }
    }
#pragma unroll
    for (int i = 0; i < 16; ++i) {
#pragma unroll
        for (int msk = 1; msk < 16; msk <<= 1) {
            float od = __shfl_xor(bd[i], msk, 64);
            int   oi = __shfl_xor(bi[i], msk, 64);
            ls[i] += __shfl_xor(ls[i], msk, 64);
            if (od < bd[i] || (od == bd[i] && oi < bi[i])) { bd[i] = od; bi[i] = oi; }
        }
    }
    if (lo == 0) {
        const int slot = (z * gridDim.y + blockIdx.y) * 2 + wc;
#pragma unroll
        for (int m = 0; m < 4; ++m)
#pragma unroll
            for (int j = 0; j < 4; ++j) {
                int row = rbase + wr * 64 + m * 16 + hi * 4 + j;
                pd [(size_t)slot * Ntot + row] = bd[m * 4 + j];
                pls[(size_t)slot * Ntot + row] = ls[m * 4 + j];
                pib[(size_t)slot * Ntot + row] = bi[m * 4 + j];
            }
    }
}

__global__ __launch_bounds__(256) void k_dist1_reduce2(
    const float* __restrict__ pd, const float* __restrict__ pls,
    const int* __restrict__ pib,
    int* __restrict__ idx_a, float* __restrict__ lse_a, float* __restrict__ inv_a,
    int* __restrict__ idx_b, float* __restrict__ lse_b, float* __restrict__ inv_b,
    int Ntot, int slots)
{
    const int z = blockIdx.y;
    int row = blockIdx.x * 256 + threadIdx.x;
    if (row >= Ntot) return;
    const float* pdz = pd + (size_t)z * slots * Ntot;
    const float* plz = pls + (size_t)z * slots * Ntot;
    const int*   piz = pib + (size_t)z * slots * Ntot;
    float bd = FLT_MAX; int bi = 0;
    float L = 0.f;
    for (int s = 0; s < slots; ++s) {
        float d = pdz[(size_t)s * Ntot + row];
        int   i = piz[(size_t)s * Ntot + row];
        if (d < bd || (d == bd && i < bi)) { bd = d; bi = i; }
        L += plz[(size_t)s * Ntot + row];
    }
    if (z) { idx_b[row] = bi; lse_b[row] = __logf(L); inv_b[row] = 1.0f / L; }
    else   { idx_a[row] = bi; lse_a[row] = __logf(L); inv_a[row] = 1.0f / L; }
}

__global__ __launch_bounds__(256) void k_mfma_dist2(
    const ushort* __restrict__ Za, const ushort* __restrict__ Zb,
    const ushort* __restrict__ CB, const float* __restrict__ cn,
    const float* __restrict__ lse_a, const float* __restrict__ lse_b,
    float* __restrict__ avg_a, float* __restrict__ avg_b,
    int Ntot, int D, int chunkCols)
{
    DBUF_DECL;
    const ushort* Z = blockIdx.z ? Zb : Za;
    const float* lse = blockIdx.z ? lse_b : lse_a;
    float* avg = blockIdx.z ? avg_b : avg_a;
    const int tid = threadIdx.x, lane = tid & 63, wid = tid >> 6;
    const int wr = wid >> 1, wc = wid & 1;
    const int rbase = blockIdx.x * 128;
    const int c0 = blockIdx.y * chunkCols;
    const int hi = lane >> 4, lo = lane & 15;
    const int KS = D >> 5, TILES = chunkCols >> 7;
    const size_t o64 = (size_t)64 * D;
    const ptrdiff_t dWrapA = -(ptrdiff_t)(D - 32);
    const ptrdiff_t dWrapB = (ptrdiff_t)128 * D - (ptrdiff_t)(D - 32);

    float lr[16];
#pragma unroll
    for (int m = 0; m < 4; ++m)
#pragma unroll
        for (int j = 0; j < 4; ++j)
            lr[m * 4 + j] = lse[rbase + wr * 64 + m * 16 + hi * 4 + j];

    const ushort* pa = stage_ptr(Z, D, rbase, tid);
    const ushort* pb = stage_ptr(CB, D, c0, tid);
    stage_issue2(pa, pb, o64, o64, AS(0), BS(0), tid);
    __syncthreads();
    int phase = 0;
    for (int t = 0; t < TILES; ++t) {
        f32x4 acc[4][4];
#pragma unroll
        for (int m = 0; m < 4; ++m)
#pragma unroll
            for (int n = 0; n < 4; ++n)
#pragma unroll
                for (int j = 0; j < 4; ++j) acc[m][n][j] = 0.f;
        for (int ks = 0; ks < KS; ++ks) {
            const bool wrap = (ks + 1 == KS);
            pa += wrap ? dWrapA : 32;
            pb += wrap ? dWrapB : 32;
            if (!(wrap && t + 1 == TILES))
                stage_issue2(pa, pb, o64, o64, AS(phase ^ 1), BS(phase ^ 1), tid);
            mma_tile(AS(phase), BS(phase), wr, wc, lane, acc);
            __syncthreads();
            phase ^= 1;
        }
        const int cbase = c0 + (t << 7) + wc * 64;
        float cnv[4];
#pragma unroll
        for (int n = 0; n < 4; ++n) cnv[n] = cn[cbase + n * 16 + lo];
        float colsum[4] = {0.f, 0.f, 0.f, 0.f};
#pragma unroll
        for (int m = 0; m < 4; ++m)
#pragma unroll
            for (int j = 0; j < 4; ++j) {
                const int i = m * 4 + j;
#pragma unroll
                for (int n = 0; n < 4; ++n) {
                    float d = sqrtf(fmaxf(1.0f + cnv[n] - 2.0f * acc[m][n][j], 0.f));
                    colsum[n] += __expf(-5.0f * d - lr[i]);
                }
            }
#pragma unroll
        for (int n = 0; n < 4; ++n) {
            float cs = colsum[n];
            cs += __shfl_xor(cs, 16, 64);
            cs += __shfl_xor(cs, 32, 64);
            if (hi == 0) atomicAdd(&avg[cbase + n * 16 + lo], cs);
        }
    }
}

__global__ __launch_bounds__(256) void k_sum_log_reduce(
    const float* __restrict__ pl, float* __restrict__ out, int Ntot, int slots)
{
    int row = blockIdx.x * 256 + threadIdx.x;
    if (row >= Ntot) return;
    float L = 0.f;
    for (int s = 0; s < slots; ++s)
        L += pl[(size_t)s * Ntot + row];
    out[row] = __logf(L);
}

__global__ __launch_bounds__(256) void k_log_inplace(
    const float* __restrict__ src, float* __restrict__ dst, int n)
{
    int i = blockIdx.x * 256 + threadIdx.x;
    if (i < n) dst[i] = __logf(src[i]);
}

// ---------------------------------------------------------------------------
// rec/match/diag on bf16 inputs: linear decomposition, 6 atomics/block.
// ---------------------------------------------------------------------------
__global__ __launch_bounds__(256) void k_rec_match(
    const ushort* __restrict__ za, const ushort* __restrict__ zb,
    const ushort* __restrict__ cbk,
    const int* __restrict__ idx_a, const int* __restrict__ idx_b,
    const float* __restrict__ lse_ab, const float* __restrict__ lse_ba,
    float* __restrict__ acc, int N, int D)
{
    const int tid = threadIdx.x, lane = tid & 63, wid = tid >> 6;
    const int gw = blockIdx.x * 4 + wid;
    const int nw = gridDim.x * 4;
    const int nf8 = D >> 3;
    float pa = 0.f, pb = 0.f, pdot = 0.f;
    for (int row = gw; row < N; row += nw) {
        const int ia = idx_a[row], ib = idx_b[row];
        const uint4* pza = (const uint4*)(za + (size_t)row * D);
        const uint4* pzb = (const uint4*)(zb + (size_t)row * D);
        const uint4* pca = (const uint4*)(cbk + (size_t)ia * D);
        const uint4* pcb = (const uint4*)(cbk + (size_t)ib * D);
        for (int f = lane; f < nf8; f += 64) {
            uint4 ua = pza[f], ub = pzb[f], uc = pca[f], ud = pcb[f];
            const unsigned int* wa = (const unsigned int*)&ua;
            const unsigned int* wb = (const unsigned int*)&ub;
            const unsigned int* wc2 = (const unsigned int*)&uc;
            const unsigned int* wd = (const unsigned int*)&ud;
#pragma unroll
            for (int q = 0; q < 4; ++q) {
                float2 va = bf2x2(wa[q]), vb = bf2x2(wb[q]);
                float2 ca = bf2x2(wc2[q]), cb = bf2x2(wd[q]);
                float dx = va.x - ca.x, dy = va.y - ca.y;
                pa += dx * dx + dy * dy;
                dx = vb.x - cb.x; dy = vb.y - cb.y;
                pb += dx * dx + dy * dy;
                pdot += va.x * vb.x + va.y * vb.y;
            }
        }
    }
    float slab = 0.f, slba = 0.f, smatch = 0.f;
    for (int r = blockIdx.x * 256 + tid; r < N; r += gridDim.x * 256) {
        slab += lse_ab[r];
        slba += lse_ba[r];
        if (idx_a[r] == idx_b[r]) smatch += 1.f;
    }
#pragma unroll
    for (int msk = 1; msk < 64; msk <<= 1) {
        pa += __shfl_xor(pa, msk, 64);
        pb += __shfl_xor(pb, msk, 64);
        pdot += __shfl_xor(pdot, msk, 64);
        slab += __shfl_xor(slab, msk, 64);
        slba += __shfl_xor(slba, msk, 64);
        smatch += __shfl_xor(smatch, msk, 64);
    }
    __shared__ float red[4][6];
    if (lane == 0) {
        red[wid][0] = pa; red[wid][1] = pb; red[wid][2] = slab;
        red[wid][3] = slba; red[wid][4] = smatch; red[wid][5] = pdot;
    }
    __syncthreads();
    if (tid < 6) {
        float s = red[0][tid] + red[1][tid] + red[2][tid] + red[3][tid];
        atomicAdd(&acc[tid], s);
    }
}

// ---------------------------------------------------------------------------
// Final combine (1 block).
// ---------------------------------------------------------------------------
__global__ __launch_bounds__(256) void k_finalize(
    const float* __restrict__ avg_a, const float* __restrict__ avg_b,
    const float* __restrict__ acc, float* __restrict__ out,
    int N, int D, int K)
{
    __shared__ float red[256];
    const int tid = threadIdx.x;
    const float invN = 1.0f / (float)N;
    float sa = 0.f, sb = 0.f;
    for (int k = tid; k < K; k += 256) {
        float va = avg_a[k] * invN;
        float vb = avg_b[k] * invN;
        sa += va * logf(va + 1e-8f);
        sb += vb * logf(vb + 1e-8f);
    }
    red[tid] = sa;
    __syncthreads();
    for (int s = 128; s > 0; s >>= 1) {
        if (tid < s) red[tid] += red[tid + s];
        __syncthreads();
    }
    float entA = -red[0];
    __syncthreads();
    red[tid] = sb;
    __syncthreads();
    for (int s = 128; s > 0; s >>= 1) {
        if (tid < s) red[tid] += red[tid + s];
        __syncthreads();
    }
    if (tid == 0) {
        float entB = -red[0];
        float nd = (float)N * (float)D;
        float rec = 1.25f * (acc[0] / nd + acc[1] / nd);
        float sdot = acc[5] / 0.07f;
        float cm  = 0.5f * ((acc[2] - sdot) + (acc[3] - sdot)) * invN;
        float div = 0.5f * (entA + entB);
        out[0] = rec + 0.5f * cm - 0.1f * div;
        out[1] = acc[4] * invN;
    }
}

// ---------------------------------------------------------------------------
extern "C" void kernel_launch(void* const* d_in, const int* in_sizes, int n_in,
                              void* d_out, int out_size, void* d_ws, size_t ws_size,
                              hipStream_t stream)
{
    const float* a   = (const float*)d_in[0];
    const float* b   = (const float*)d_in[1];
    const float* Wa  = (const float*)d_in[2];
    const float* ba  = (const float*)d_in[3];
    const float* Wb  = (const float*)d_in[4];
    const float* bb  = (const float*)d_in[5];
    const float* cbk = (const float*)d_in[6];

    const int D  = in_sizes[3];            // 512
    const int dA = in_sizes[2] / D;        // 1024
    const int dB = in_sizes[4] / D;        // 1024
    const int N  = in_sizes[0] / dA;       // 8192
    const int K  = in_sizes[6] / D;        // 4096

    char* w = (char*)d_ws;
    size_t off = 0;
    auto alloc = [&](size_t bytes) -> void* {
        void* p = w + off;
        off = (off + bytes + 255) & ~(size_t)255;
        return p;
    };
    float*  za     = (float*)alloc((size_t)N * D * 4);
    float*  zb     = (float*)alloc((size_t)N * D * 4);
    float*  cn     = (float*)alloc((size_t)K * 4);
    int*    idx_a  = (int*)  alloc((size_t)N * 4);
    int*    idx_b  = (int*)  alloc((size_t)N * 4);
    float*  lse_a  = (float*)alloc((size_t)N * 4);
    float*  lse_b  = (float*)alloc((size_t)N * 4);
    float*  inv_a  = (float*)alloc((size_t)N * 4);
    float*  inv_b  = (float*)alloc((size_t)N * 4);
    float*  lse_ab = (float*)alloc((size_t)N * 4);
    float*  lse_ba = (float*)alloc((size_t)N * 4);
    float*  avgreg = (float*)alloc(((size_t)2 * K + 8) * 4);
    float*  avg_a  = avgreg;
    float*  avg_b  = avgreg + K;
    float*  accb   = avgreg + 2 * K;
    ushort* Wa_bf  = (ushort*)alloc((size_t)D * dA * 2);
    ushort* Wb_bf  = (ushort*)alloc((size_t)D * dB * 2);
    ushort* cbk_bf = (ushort*)alloc((size_t)K * D * 2);
    ushort* regionA = (ushort*)alloc((size_t)N * dA * 2);
    ushort* a_bf  = regionA;
    ushort* za_bf = regionA;
    ushort* zb_bf = regionA + (size_t)N * D;
    ushort* regionB = (ushort*)alloc((size_t)N * dB * 2);
    ushort* b_bf   = regionB;
    float* pl     = (float*)regionB;               // 32*N
    float* pd     = pl  + (size_t)32 * N;          // 64*N (fallback)
    float* pls    = pd  + (size_t)64 * N;          // 64*N (fallback)
    int*   pib    = (int*)(pls + (size_t)64 * N);  // 64*N (fallback)
    float* colsum = (float*)(pib + (size_t)64 * N); // N
    if (off > ws_size) return;
    ushort* expm_a = (ushort*)alloc((size_t)N * K * 2);
    ushort* expm_b = (ushort*)alloc((size_t)N * K * 2);
    const bool useExp = (off <= ws_size);

    dim3 blk(256);
    dim3 blk8(512);

    // bf16 conversions
    k_cvt_bf16<<<1024, blk, 0, stream>>>(a,   a_bf,   (size_t)N * dA);
    k_cvt_bf16<<<1024, blk, 0, stream>>>(b,   b_bf,   (size_t)N * dB);
    k_cvt_bf16<<<256,  blk, 0, stream>>>(Wa,  Wa_bf,  (size_t)D * dA);
    k_cvt_bf16<<<256,  blk, 0, stream>>>(Wb,  Wb_bf,  (size_t)D * dB);
    k_cvt_bf16<<<512,  blk, 0, stream>>>(cbk, cbk_bf, (size_t)K * D);

    // projections (fused a/b)
    k_mfma_gemm_bias2<<<dim3(N / 128, D / 128, 2), blk, 0, stream>>>(
        a_bf, Wa_bf, ba, za, b_bf, Wb_bf, bb, zb, D, dA);

    // normalize both + codebook norms
    k_normalize2<<<dim3((N + 3) / 4, 2), blk, 0, stream>>>(za, za_bf, zb, zb_bf, N, D);
    k_rownorm2<<<dim3((K + 3) / 4), blk, 0, stream>>>(cbk, cn, K, D);
    hipMemsetAsync(avgreg, 0, ((size_t)2 * K + 8) * 4, stream);
    hipMemsetAsync(colsum, 0, (size_t)N * 4, stream);

    // distances
    if (useExp) {
        const int dchunk = 1024;                       // 4 col-tiles of 256
        k_dist8<<<dim3(N / 256, K / dchunk, 2), blk8, 0, stream>>>(
            za_bf, zb_bf, cbk_bf, cn, expm_a, expm_b, N, K, D, dchunk);
        k_row_stats<<<dim3(N / 4, 2), blk, 0, stream>>>(
            expm_a, expm_b, idx_a, lse_a, inv_a, idx_b, lse_b, inv_b, K);
        k_avg_stream<<<dim3(K / 1024, N / 64, 2), blk, 0, stream>>>(
            expm_a, expm_b, inv_a, inv_b, avg_a, avg_b, K, 64);
    } else {
        const int dchunk = 256, dcy = K / dchunk;
        dim3 dgrid(N / 128, dcy, 2);
        k_mfma_dist1_noexp<<<dgrid, blk, 0, stream>>>(
            za_bf, zb_bf, cbk_bf, cn, pd, pls, pib, N, D, dchunk);
        k_dist1_reduce2<<<dim3(N / 256, 2), blk, 0, stream>>>(
            pd, pls, pib, idx_a, lse_a, inv_a, idx_b, lse_b, inv_b, N, 2 * dcy);
        k_mfma_dist2<<<dgrid, blk, 0, stream>>>(
            za_bf, zb_bf, cbk_bf, cn, lse_a, lse_b, avg_a, avg_b, N, D, dchunk);
    }

    // contrastive: one 8-wave pass -> row exp-sums (pl slots) + col exp-sums
    const int schunk = 1024, scy = N / schunk;         // grid (32, 8) = 256 blocks
    k_sim8<<<dim3(N / 256, scy), blk8, 0, stream>>>(za_bf, zb_bf, pl, colsum, N, D, schunk);
    k_sum_log_reduce<<<N / 256, blk, 0, stream>>>(pl, lse_ab, N, 4 * scy);
    k_log_inplace<<<N / 256, blk, 0, stream>>>(colsum, lse_ba, N);

    // rec/match/diag + final combine
    k_rec_match<<<256, blk, 0, stream>>>(za_bf, zb_bf, cbk_bf, idx_a, idx_b, lse_ab, lse_ba, accb, N, D);
    k_finalize<<<1, blk, 0, stream>>>(avg_a, avg_b, accb, (float*)d_out, N, D, K);
}